// Round 8
// baseline (1857.718 us; speedup 1.0000x reference)
//
#include <hip/hip_runtime.h>
#include <hip/hip_bf16.h>
#include <float.h>

#define NG    32
#define PTS   1024
#define NPTS  (NG*PTS)      // 32768
#define KNN   30
#define DIM   64
#define CHUNK 8192
#define NGC   4             // graphs per D-chunk

typedef __attribute__((ext_vector_type(8))) short bf16x8;
typedef __attribute__((ext_vector_type(4))) float f32x4;
typedef unsigned short ushort_t;

__device__ inline void bfsplit(float v, ushort_t& h, ushort_t& l) {
    __hip_bfloat16 bh = __float2bfloat16(v);
    float r = v - __bfloat162float(bh);
    __hip_bfloat16 bl = __float2bfloat16(r);
    h = *reinterpret_cast<ushort_t*>(&bh);
    l = *reinterpret_cast<ushort_t*>(&bl);
}

// ---------------------------------------------------------------------------
// prep: S32/S64 + transpose XT[f][p] (for fb_k) + bf16 hi/lo rows [p][KP]
// ---------------------------------------------------------------------------
template<int F, int KP>
__global__ __launch_bounds__(256) void prep_k(const float* __restrict__ X, int ldx,
                                              float* __restrict__ S32,
                                              double* __restrict__ S64,
                                              float* __restrict__ XT,
                                              ushort_t* __restrict__ Xh,
                                              ushort_t* __restrict__ Xl) {
    int p = blockIdx.x * 256 + threadIdx.x;
    float s32 = 0.f;
    double s64 = 0.0;
    #pragma unroll
    for (int f = 0; f < F; ++f) {
        float v = X[(size_t)p * ldx + f];
        s32 = fmaf(v, v, s32);
        s64 = fma((double)v, (double)v, s64);
        XT[(size_t)f * NPTS + p] = v;
        bfsplit(v, Xh[(size_t)p * KP + f], Xl[(size_t)p * KP + f]);
    }
    #pragma unroll
    for (int f = F; f < KP; ++f) {
        Xh[(size_t)p * KP + f] = 0;
        Xl[(size_t)p * KP + f] = 0;
    }
    S32[p] = s32;
    S64[p] = s64;
}

// per-graph max of S32 + zero the overflow counter
__global__ __launch_bounds__(256) void smax_k(const float* __restrict__ S32,
                                              float* __restrict__ SMAX,
                                              int* __restrict__ ovf_cnt) {
    if (blockIdx.x == 0 && threadIdx.x == 0) *ovf_cnt = 0;
    int g = blockIdx.x;
    int lane = threadIdx.x & 63, wv = threadIdx.x >> 6;
    float m = 0.f;
    for (int t = threadIdx.x; t < PTS; t += 256) m = fmaxf(m, S32[(size_t)g * PTS + t]);
    #pragma unroll
    for (int off = 32; off; off >>= 1) m = fmaxf(m, __shfl_xor(m, off));
    __shared__ float wm[4];
    if (lane == 0) wm[wv] = m;
    __syncthreads();
    if (threadIdx.x == 0)
        SMAX[g] = fmaxf(fmaxf(wm[0], wm[1]), fmaxf(wm[2], wm[3]));
}

// ---------------------------------------------------------------------------
// dist_k: D[i][j] = si + sj - 2*dot(x_i,x_j) via MFMA (bf16 hi/lo 3-product).
// Grid: (8 j-tiles, 8 i-tiles, NGC graphs). 128x128 per block, 4 waves 2x2.
// ---------------------------------------------------------------------------
template<int KP>
__global__ __launch_bounds__(256) void dist_k(const ushort_t* __restrict__ Xh,
                                              const ushort_t* __restrict__ Xl,
                                              const float* __restrict__ S32,
                                              float* __restrict__ D,
                                              int gbase) {
    constexpr int KS = KP / 32;
    int lane = threadIdx.x & 63, wv = threadIdx.x >> 6;
    int wr = wv >> 1, wc = wv & 1;
    int col16 = lane & 15, grp = lane >> 4, grp8 = grp << 3;
    int gz = blockIdx.z;
    int p0 = (gbase + gz) * PTS;
    int bm = blockIdx.y * 128, bn = blockIdx.x * 128;

    bf16x8 ah[4][KS], al[4][KS];
    float4 si4[4];
    #pragma unroll
    for (int mf = 0; mf < 4; ++mf) {
        int r = bm + wr * 64 + mf * 16 + col16;
        #pragma unroll
        for (int ks = 0; ks < KS; ++ks) {
            ah[mf][ks] = *reinterpret_cast<const bf16x8*>(&Xh[(size_t)(p0 + r) * KP + ks * 32 + grp8]);
            al[mf][ks] = *reinterpret_cast<const bf16x8*>(&Xl[(size_t)(p0 + r) * KP + ks * 32 + grp8]);
        }
        si4[mf] = *reinterpret_cast<const float4*>(&S32[p0 + bm + wr * 64 + mf * 16 + grp * 4]);
    }
    #pragma unroll
    for (int nf = 0; nf < 4; ++nf) {
        int c = bn + wc * 64 + nf * 16 + col16;
        bf16x8 bh[KS], bl[KS];
        #pragma unroll
        for (int ks = 0; ks < KS; ++ks) {
            bh[ks] = *reinterpret_cast<const bf16x8*>(&Xh[(size_t)(p0 + c) * KP + ks * 32 + grp8]);
            bl[ks] = *reinterpret_cast<const bf16x8*>(&Xl[(size_t)(p0 + c) * KP + ks * 32 + grp8]);
        }
        float sj = S32[p0 + c];
        #pragma unroll
        for (int mf = 0; mf < 4; ++mf) {
            f32x4 acc = {0.f, 0.f, 0.f, 0.f};
            #pragma unroll
            for (int ks = 0; ks < KS; ++ks) {
                acc = __builtin_amdgcn_mfma_f32_16x16x32_bf16(ah[mf][ks], bh[ks], acc, 0, 0, 0);
                acc = __builtin_amdgcn_mfma_f32_16x16x32_bf16(ah[mf][ks], bl[ks], acc, 0, 0, 0);
                acc = __builtin_amdgcn_mfma_f32_16x16x32_bf16(al[mf][ks], bh[ks], acc, 0, 0, 0);
            }
            size_t rowbase = (size_t)(gz * PTS + bm + wr * 64 + mf * 16 + grp * 4);
            #pragma unroll
            for (int rg = 0; rg < 4; ++rg)
                D[(rowbase + rg) * 1024 + bn + wc * 64 + nf * 16 + col16] =
                    (si4[mf][rg] + sj) - 2.f * acc[rg];
        }
    }
}

// ---------------------------------------------------------------------------
// sel_k: selection only. d32 rows from D -> bisection -> compact (superset of
// f64 top-30; eps covers bf16 3-product error) -> exact f64 rescore -> bitonic.
// ---------------------------------------------------------------------------
template<int F>
__global__ __launch_bounds__(256) void sel_k(const float* __restrict__ X, int ldx,
                                             const float* __restrict__ D,
                                             const float* __restrict__ S32,
                                             const double* __restrict__ S64,
                                             const float* __restrict__ SMAX,
                                             int* __restrict__ IDX,
                                             int* __restrict__ ovf_cnt,
                                             int* __restrict__ ovf_list,
                                             int gbase) {
    int wv = threadIdx.x >> 6, lane = threadIdx.x & 63;
    int l0 = blockIdx.x * 16;                  // local base within chunk
    int i0 = gbase * PTS + l0;                 // global base
    int base = i0 & ~(PTS - 1);
    __shared__ float xis[16][F];
    __shared__ int surv[4][4][64];
    for (int l = threadIdx.x; l < 16 * F; l += 256) {
        int pt = l / F, f = l - pt * F;
        xis[pt][f] = X[(size_t)(i0 + pt) * ldx + f];
    }
    __syncthreads();
    float smax = SMAX[i0 >> 10];

    float si[4];
    float d32[4][16];
    #pragma unroll
    for (int ii = 0; ii < 4; ++ii) {
        si[ii] = S32[i0 + wv * 4 + ii];
        #pragma unroll
        for (int m = 0; m < 4; ++m) {
            const float4 v = *reinterpret_cast<const float4*>(
                &D[(size_t)(l0 + wv * 4 + ii) * 1024 + (m << 8) + (lane << 2)]);
            d32[ii][m * 4 + 0] = v.x; d32[ii][m * 4 + 1] = v.y;
            d32[ii][m * 4 + 2] = v.z; d32[ii][m * 4 + 3] = v.w;
        }
    }

    const unsigned long long below = (1ull << lane) - 1;
    #pragma unroll
    for (int ii = 0; ii < 4; ++ii) {
        int i = i0 + wv * 4 + ii;
        float lo = -1.f, hi = 2.f * (si[ii] + smax) + 1.f;
        for (int it = 0; it < 32; ++it) {
            float piv = 0.5f * (lo + hi);
            int cnt = 0;
            #pragma unroll
            for (int r = 0; r < 16; ++r)
                cnt += __popcll(__ballot(d32[ii][r] <= piv));
            if (cnt >= KNN) { hi = piv; if (cnt <= 56) break; }
            else lo = piv;
        }
        // eps: >=4x the bf16 hi/lo 3-product distance error bound (~2.3e-5*(si+sj))
        float T = hi + 1.0e-4f * (si[ii] + smax);

        int total = 0;
        #pragma unroll
        for (int r = 0; r < 16; ++r) {
            bool pred = d32[ii][r] <= T;
            unsigned long long mask = __ballot(pred);
            if (pred) {
                int slot = total + __popcll(mask & below);
                if (slot < 64)
                    surv[wv][ii][slot] = ((r >> 2) << 8) + (lane << 2) + (r & 3);
            }
            total += __popcll(mask);
        }
        if (total > 64) {
            if (lane == 0) ovf_list[atomicAdd(ovf_cnt, 1)] = i;
            continue;
        }
        __builtin_amdgcn_wave_barrier();
        asm volatile("s_waitcnt lgkmcnt(0)" ::: "memory");

        double d64 = DBL_MAX;
        int jabs = 0x7fffffff;
        if (lane < total) {
            int jl = surv[wv][ii][lane];
            jabs = base + jl;
            const float* xj = X + (size_t)jabs * ldx;
            double dot = 0.0;
            #pragma unroll
            for (int f = 0; f < F; ++f)
                dot = fma((double)xis[wv * 4 + ii][f], (double)xj[f], dot);
            d64 = (S64[i] + S64[jabs]) - 2.0 * dot;
        }
        #pragma unroll
        for (int k = 2; k <= 64; k <<= 1) {
            #pragma unroll
            for (int s = k >> 1; s > 0; s >>= 1) {
                double od = __shfl_xor(d64, s);
                int oj = __shfl_xor(jabs, s);
                bool otherSmaller = (od < d64) || (od == d64 && oj < jabs);
                bool keepSmaller = (((lane & k) == 0) == ((lane & s) == 0));
                if (otherSmaller == keepSmaller) { d64 = od; jabs = oj; }
            }
        }
        if (lane < KNN) IDX[(size_t)i * KNN + lane] = jabs;
        __builtin_amdgcn_wave_barrier();
    }
}

// ---------------------------------------------------------------------------
// fb_k: exact f64 full scan + 30x min-extract for overflow points only.
// ---------------------------------------------------------------------------
template<int F>
__global__ __launch_bounds__(256) void fb_k(const float* __restrict__ X, int ldx,
                                            const float* __restrict__ XT,
                                            const double* __restrict__ S64,
                                            int* __restrict__ IDX,
                                            const int* __restrict__ ovf_cnt,
                                            const int* __restrict__ ovf_list) {
    int wv = threadIdx.x >> 6, lane = threadIdx.x & 63;
    int novf = *ovf_cnt;
    __shared__ double xis[4][F];
    for (int t = blockIdx.x * 4 + wv; t < novf; t += 64 * 4) {
        int i = ovf_list[t];
        int base = i & ~(PTS - 1);
        if (lane < F) xis[wv][lane] = (double)X[(size_t)i * ldx + lane];
        __builtin_amdgcn_wave_barrier();
        asm volatile("s_waitcnt lgkmcnt(0)" ::: "memory");
        double dd[16];
        #pragma unroll
        for (int m = 0; m < 4; ++m) {
            int j0 = (m << 8) + (lane << 2);
            double d0 = 0.0, d1 = 0.0, d2 = 0.0, d3 = 0.0;
            #pragma unroll
            for (int f = 0; f < F; ++f) {
                double xif = xis[wv][f];
                const float4 xj = *reinterpret_cast<const float4*>(&XT[(size_t)f * NPTS + base + j0]);
                d0 = fma(xif, (double)xj.x, d0);
                d1 = fma(xif, (double)xj.y, d1);
                d2 = fma(xif, (double)xj.z, d2);
                d3 = fma(xif, (double)xj.w, d3);
            }
            dd[m * 4 + 0] = (S64[i] + S64[base + j0 + 0]) - 2.0 * d0;
            dd[m * 4 + 1] = (S64[i] + S64[base + j0 + 1]) - 2.0 * d1;
            dd[m * 4 + 2] = (S64[i] + S64[base + j0 + 2]) - 2.0 * d2;
            dd[m * 4 + 3] = (S64[i] + S64[base + j0 + 3]) - 2.0 * d3;
        }
        for (int k = 0; k < KNN; ++k) {
            double bd = DBL_MAX;
            int bj = 0x7fffffff;
            #pragma unroll
            for (int r = 0; r < 16; ++r) {
                int j = ((r >> 2) << 8) + (lane << 2) + (r & 3);
                if (dd[r] < bd) { bd = dd[r]; bj = j; }
            }
            #pragma unroll
            for (int off = 32; off; off >>= 1) {
                double od = __shfl_xor(bd, off);
                int oj = __shfl_xor(bj, off);
                if (od < bd || (od == bd && oj < bj)) { bd = od; bj = oj; }
            }
            if (((bj >> 2) & 63) == lane) {
                int r = ((bj >> 8) << 2) | (bj & 3);
                #pragma unroll
                for (int rr = 0; rr < 16; ++rr) if (rr == r) dd[rr] = DBL_MAX;
            }
            if (lane == 0) IDX[(size_t)i * KNN + k] = base + bj;
        }
        __builtin_amdgcn_wave_barrier();
    }
}

// ---------------------------------------------------------------------------
// mg: per-point layer-1 decomposition: h1_edge = relu(m_i + g_j)
// ---------------------------------------------------------------------------
template<int F>
__global__ __launch_bounds__(256) void mg_k(const float* __restrict__ X, int ldx,
                                            const float* __restrict__ W1,
                                            const float* __restrict__ B1,
                                            float* __restrict__ Mo, float* __restrict__ Go) {
    int tid = blockIdx.x * 256 + threadIdx.x;
    int pp = tid >> 6, c = tid & 63;
    float m = B1[c], g = 0.f;
    #pragma unroll
    for (int f = 0; f < F; ++f) {
        float xv = X[(size_t)pp * ldx + f];
        float wt = W1[f * DIM + c];
        float wb = W1[(F + f) * DIM + c];
        m = fmaf(xv, wt - wb, m);
        g = fmaf(xv, wb, g);
    }
    Mo[(size_t)pp * DIM + c] = m;
    Go[(size_t)pp * DIM + c] = g;
}

// ---------------------------------------------------------------------------
// edge (MFMA): per wave = 1 point; h1[32x64] @ W2[64x64], bf16 hi/lo 3-product
// ---------------------------------------------------------------------------
__global__ __launch_bounds__(256) void edge_k(const int* __restrict__ IDX,
                                              const float* __restrict__ G,
                                              const float* __restrict__ Mb,
                                              const float* __restrict__ W2,
                                              const float* __restrict__ B2,
                                              float* __restrict__ OUT, int ldo) {
    __shared__ ushort_t w2hi[64][72], w2lo[64][72];
    __shared__ ushort_t h1hi[4][32][72], h1lo[4][32][72];
    int wv = threadIdx.x >> 6, lane = threadIdx.x & 63;
    int i = blockIdx.x * 4 + wv;
    int col16 = lane & 15, grp = lane >> 4, grp8 = (lane >> 4) << 3;

    for (int l = threadIdx.x; l < 4096; l += 256) {
        int c = l & 63, k = l >> 6;
        bfsplit(W2[k * 64 + c], w2hi[c][k], w2lo[c][k]);
    }
    __syncthreads();

    float mi = Mb[(size_t)i * DIM + lane];
    const int* idxrow = IDX + (size_t)i * KNN;
    int idxv = (lane < KNN) ? idxrow[lane] : 0;
    float g[KNN];
    #pragma unroll
    for (int nb = 0; nb < KNN; ++nb) {
        int j = __shfl(idxv, nb);
        g[nb] = G[(size_t)j * DIM + lane];
    }
    #pragma unroll
    for (int nb = 0; nb < KNN; ++nb) {
        float h = fmaxf(mi + g[nb], 0.f);
        bfsplit(h, h1hi[wv][nb][lane], h1lo[wv][nb][lane]);
    }
    h1hi[wv][30][lane] = 0; h1lo[wv][30][lane] = 0;
    h1hi[wv][31][lane] = 0; h1lo[wv][31][lane] = 0;
    __builtin_amdgcn_wave_barrier();
    asm volatile("s_waitcnt lgkmcnt(0)" ::: "memory");

    bf16x8 ahi[2][2], alo[2][2];
    #pragma unroll
    for (int m = 0; m < 2; ++m)
        #pragma unroll
        for (int ks = 0; ks < 2; ++ks) {
            ahi[m][ks] = *reinterpret_cast<const bf16x8*>(&h1hi[wv][m * 16 + col16][ks * 32 + grp8]);
            alo[m][ks] = *reinterpret_cast<const bf16x8*>(&h1lo[wv][m * 16 + col16][ks * 32 + grp8]);
        }

    float myout = 0.f;
    #pragma unroll
    for (int n = 0; n < 4; ++n) {
        bf16x8 bhi[2], blo[2];
        #pragma unroll
        for (int ks = 0; ks < 2; ++ks) {
            bhi[ks] = *reinterpret_cast<const bf16x8*>(&w2hi[n * 16 + col16][ks * 32 + grp8]);
            blo[ks] = *reinterpret_cast<const bf16x8*>(&w2lo[n * 16 + col16][ks * 32 + grp8]);
        }
        f32x4 acc0 = {0.f, 0.f, 0.f, 0.f}, acc1 = {0.f, 0.f, 0.f, 0.f};
        #pragma unroll
        for (int ks = 0; ks < 2; ++ks) {
            acc0 = __builtin_amdgcn_mfma_f32_16x16x32_bf16(ahi[0][ks], bhi[ks], acc0, 0, 0, 0);
            acc1 = __builtin_amdgcn_mfma_f32_16x16x32_bf16(ahi[1][ks], bhi[ks], acc1, 0, 0, 0);
            acc0 = __builtin_amdgcn_mfma_f32_16x16x32_bf16(ahi[0][ks], blo[ks], acc0, 0, 0, 0);
            acc1 = __builtin_amdgcn_mfma_f32_16x16x32_bf16(ahi[1][ks], blo[ks], acc1, 0, 0, 0);
            acc0 = __builtin_amdgcn_mfma_f32_16x16x32_bf16(alo[0][ks], bhi[ks], acc0, 0, 0, 0);
            acc1 = __builtin_amdgcn_mfma_f32_16x16x32_bf16(alo[1][ks], bhi[ks], acc1, 0, 0, 0);
        }
        float cm = fmaxf(fmaxf(acc0[0], acc0[1]), fmaxf(acc0[2], acc0[3]));
        cm = fmaxf(cm, fmaxf(acc1[0], acc1[1]));
        if (grp < 3) cm = fmaxf(cm, fmaxf(acc1[2], acc1[3]));
        cm = fmaxf(cm, __shfl_xor(cm, 16));
        cm = fmaxf(cm, __shfl_xor(cm, 32));
        if (grp == n) myout = cm;
    }
    OUT[(size_t)i * ldo + lane] = fmaxf(myout + B2[lane], 0.f);
}

// ---------------------------------------------------------------------------
// wcvt: one-time W[K][N] -> W^T hi/lo bf16 [N][K]
// ---------------------------------------------------------------------------
__global__ __launch_bounds__(256) void wcvt_k(const float* __restrict__ W, int K, int N,
                                              ushort_t* __restrict__ Th,
                                              ushort_t* __restrict__ Tl) {
    int idx = blockIdx.x * 256 + threadIdx.x;
    if (idx >= K * N) return;
    int k = idx / N, n = idx - k * N;
    ushort_t h, l;
    bfsplit(W[idx], h, l);
    Th[(size_t)n * K + k] = h;
    Tl[(size_t)n * K + k] = l;
}

// ---------------------------------------------------------------------------
// gemmx: MFMA GEMM, 128x128 tile, BK=32, bf16 hi/lo 3-product.
// ---------------------------------------------------------------------------
template<bool A32, bool OUT16, bool RELU>
__global__ __launch_bounds__(256) void gemmx_k(
    const float* __restrict__ Afp,
    const ushort_t* __restrict__ Agh, const ushort_t* __restrict__ Agl, int Kd,
    const ushort_t* __restrict__ Bth, const ushort_t* __restrict__ Btl,
    int N, const float* __restrict__ Bias,
    float* __restrict__ Cfp, ushort_t* __restrict__ Cgh, ushort_t* __restrict__ Cgl) {
    constexpr int BM = 128, BN = 128, BKP = 40;
    __shared__ ushort_t Ah[BM][BKP], Al[BM][BKP], Bh[BN][BKP], Bl[BN][BKP];
    int tid = threadIdx.x;
    int lane = tid & 63, wv = tid >> 6;
    int wr = wv >> 1, wc = wv & 1;
    int col16 = lane & 15, grp = lane >> 4, grp8 = grp << 3;
    int bm = blockIdx.y * BM, bn = blockIdx.x * BN;
    f32x4 acc[4][4];
    #pragma unroll
    for (int mf = 0; mf < 4; ++mf)
        #pragma unroll
        for (int nf = 0; nf < 4; ++nf) acc[mf][nf] = (f32x4){0.f, 0.f, 0.f, 0.f};

    for (int k0 = 0; k0 < Kd; k0 += 32) {
        if constexpr (A32) {
            for (int l = tid; l < BM * 8; l += 256) {
                int r = l >> 3, c4 = (l & 7) << 2;
                const float4 a = *reinterpret_cast<const float4*>(&Afp[(size_t)(bm + r) * Kd + k0 + c4]);
                ushort4 h4, l4;
                bfsplit(a.x, h4.x, l4.x);
                bfsplit(a.y, h4.y, l4.y);
                bfsplit(a.z, h4.z, l4.z);
                bfsplit(a.w, h4.w, l4.w);
                *reinterpret_cast<ushort4*>(&Ah[r][c4]) = h4;
                *reinterpret_cast<ushort4*>(&Al[r][c4]) = l4;
            }
        } else {
            for (int l = tid; l < BM * 4; l += 256) {
                int r = l >> 2, q = (l & 3) << 3;
                *reinterpret_cast<uint4*>(&Ah[r][q]) =
                    *reinterpret_cast<const uint4*>(&Agh[(size_t)(bm + r) * Kd + k0 + q]);
                *reinterpret_cast<uint4*>(&Al[r][q]) =
                    *reinterpret_cast<const uint4*>(&Agl[(size_t)(bm + r) * Kd + k0 + q]);
            }
        }
        for (int l = tid; l < BN * 4; l += 256) {
            int n = l >> 2, q = (l & 3) << 3;
            *reinterpret_cast<uint4*>(&Bh[n][q]) =
                *reinterpret_cast<const uint4*>(&Bth[(size_t)(bn + n) * Kd + k0 + q]);
            *reinterpret_cast<uint4*>(&Bl[n][q]) =
                *reinterpret_cast<const uint4*>(&Btl[(size_t)(bn + n) * Kd + k0 + q]);
        }
        __syncthreads();

        bf16x8 afh[4], afl[4], bfh[4], bfl[4];
        #pragma unroll
        for (int mf = 0; mf < 4; ++mf) {
            afh[mf] = *reinterpret_cast<const bf16x8*>(&Ah[wr * 64 + mf * 16 + col16][grp8]);
            afl[mf] = *reinterpret_cast<const bf16x8*>(&Al[wr * 64 + mf * 16 + col16][grp8]);
        }
        #pragma unroll
        for (int nf = 0; nf < 4; ++nf) {
            bfh[nf] = *reinterpret_cast<const bf16x8*>(&Bh[wc * 64 + nf * 16 + col16][grp8]);
            bfl[nf] = *reinterpret_cast<const bf16x8*>(&Bl[wc * 64 + nf * 16 + col16][grp8]);
        }
        #pragma unroll
        for (int mf = 0; mf < 4; ++mf)
            #pragma unroll
            for (int nf = 0; nf < 4; ++nf) {
                acc[mf][nf] = __builtin_amdgcn_mfma_f32_16x16x32_bf16(afh[mf], bfh[nf], acc[mf][nf], 0, 0, 0);
                acc[mf][nf] = __builtin_amdgcn_mfma_f32_16x16x32_bf16(afh[mf], bfl[nf], acc[mf][nf], 0, 0, 0);
                acc[mf][nf] = __builtin_amdgcn_mfma_f32_16x16x32_bf16(afl[mf], bfh[nf], acc[mf][nf], 0, 0, 0);
            }
        __syncthreads();
    }

    #pragma unroll
    for (int nf = 0; nf < 4; ++nf) {
        int col = bn + wc * 64 + nf * 16 + col16;
        float b = Bias[col];
        #pragma unroll
        for (int mf = 0; mf < 4; ++mf) {
            #pragma unroll
            for (int rg = 0; rg < 4; ++rg) {
                int row = bm + wr * 64 + mf * 16 + grp * 4 + rg;
                float v = acc[mf][nf][rg] + b;
                if (RELU) v = fmaxf(v, 0.f);
                if constexpr (OUT16) {
                    bfsplit(v, Cgh[(size_t)row * N + col], Cgl[(size_t)row * N + col]);
                } else {
                    Cfp[(size_t)row * N + col] = v;
                }
            }
        }
    }
}

// ---------------------------------------------------------------------------
// fp32 tiled GEMM (small tail layers)
// ---------------------------------------------------------------------------
template<int TM, int TN, int BK, bool RELU>
__global__ __launch_bounds__(256) void gemm_k(const float* __restrict__ A, int Kd,
                                              const float* __restrict__ W, int N,
                                              const float* __restrict__ Bias,
                                              float* __restrict__ C) {
    constexpr int MM = TM / 16, MN = TN / 16;
    __shared__ __align__(16) float As_t[BK][TM + 4];
    __shared__ __align__(16) float Ws[BK][TN];
    int bm = blockIdx.y * TM, bn = blockIdx.x * TN;
    int tid = threadIdx.x;
    int tr = tid >> 4, tc = tid & 15;
    float acc[MM][MN] = {};
    for (int k0 = 0; k0 < Kd; k0 += BK) {
        #pragma unroll
        for (int l = tid; l < TM * (BK / 4); l += 256) {
            int r = l / (BK / 4), q = l & (BK / 4 - 1);
            const float4 a4 = *reinterpret_cast<const float4*>(&A[(size_t)(bm + r) * Kd + k0 + 4 * q]);
            As_t[4 * q + 0][r] = a4.x;
            As_t[4 * q + 1][r] = a4.y;
            As_t[4 * q + 2][r] = a4.z;
            As_t[4 * q + 3][r] = a4.w;
        }
        #pragma unroll
        for (int l = tid; l < BK * (TN / 4); l += 256) {
            int r = l / (TN / 4), q = l & (TN / 4 - 1);
            *reinterpret_cast<float4*>(&Ws[r][4 * q]) =
                *reinterpret_cast<const float4*>(&W[(size_t)(k0 + r) * N + bn + 4 * q]);
        }
        __syncthreads();
        #pragma unroll
        for (int kk = 0; kk < BK; ++kk) {
            float a[MM], w[MN];
            #pragma unroll
            for (int u = 0; u < MM; u += 4) {
                const float4 v4 = *reinterpret_cast<const float4*>(&As_t[kk][tr * MM + u]);
                a[u] = v4.x; a[u + 1] = v4.y; a[u + 2] = v4.z; a[u + 3] = v4.w;
            }
            #pragma unroll
            for (int v = 0; v < MN; v += 4) {
                const float4 v4 = *reinterpret_cast<const float4*>(&Ws[kk][tc * MN + v]);
                w[v] = v4.x; w[v + 1] = v4.y; w[v + 2] = v4.z; w[v + 3] = v4.w;
            }
            #pragma unroll
            for (int u = 0; u < MM; ++u)
                #pragma unroll
                for (int v = 0; v < MN; ++v)
                    acc[u][v] = fmaf(a[u], w[v], acc[u][v]);
        }
        __syncthreads();
    }
    #pragma unroll
    for (int u = 0; u < MM; ++u) {
        int row = bm + tr * MM + u;
        #pragma unroll
        for (int v = 0; v < MN; v += 4) {
            int col = bn + tc * MN + v;
            float4 o;
            o.x = acc[u][v + 0] + Bias[col + 0];
            o.y = acc[u][v + 1] + Bias[col + 1];
            o.z = acc[u][v + 2] + Bias[col + 2];
            o.w = acc[u][v + 3] + Bias[col + 3];
            if (RELU) {
                o.x = fmaxf(o.x, 0.f); o.y = fmaxf(o.y, 0.f);
                o.z = fmaxf(o.z, 0.f); o.w = fmaxf(o.w, 0.f);
            }
            *reinterpret_cast<float4*>(&C[(size_t)row * N + col]) = o;
        }
    }
}

// ---------------------------------------------------------------------------
template<int F, int KP>
static void run_conv(const float* Xin, int ldx,
                     const float* W1, const float* B1,
                     const float* W2, const float* B2,
                     float* OUT, int ldo,
                     float* XT, float* S32, double* S64, float* SMAX,
                     ushort_t* Xbh, ushort_t* Xbl, float* Dbuf,
                     float* Mb, float* Gb, int* IDX,
                     int* ovf_cnt, int* ovf_list,
                     hipStream_t stream) {
    prep_k<F, KP><<<NPTS / 256, 256, 0, stream>>>(Xin, ldx, S32, S64, XT, Xbh, Xbl);
    smax_k<<<NG, 256, 0, stream>>>(S32, SMAX, ovf_cnt);
    for (int c = 0; c < NG / NGC; ++c) {
        dist_k<KP><<<dim3(8, 8, NGC), 256, 0, stream>>>(Xbh, Xbl, S32, Dbuf, c * NGC);
        sel_k<F><<<NGC * PTS / 16, 256, 0, stream>>>(Xin, ldx, Dbuf, S32, S64, SMAX,
                                                     IDX, ovf_cnt, ovf_list, c * NGC);
    }
    fb_k<F><<<64, 256, 0, stream>>>(Xin, ldx, XT, S64, IDX, ovf_cnt, ovf_list);
    mg_k<F><<<NPTS * DIM / 256, 256, 0, stream>>>(Xin, ldx, W1, B1, Mb, Gb);
    edge_k<<<NPTS / 4, 256, 0, stream>>>(IDX, Gb, Mb, W2, B2, OUT, ldo);
}

extern "C" void kernel_launch(void* const* d_in, const int* in_sizes, int n_in,
                              void* d_out, int out_size, void* d_ws, size_t ws_size,
                              hipStream_t stream) {
    (void)in_sizes; (void)n_in; (void)out_size; (void)ws_size;
    const float* x    = (const float*)d_in[0];
    const float* c1w1 = (const float*)d_in[2];  const float* c1b1 = (const float*)d_in[3];
    const float* c1w2 = (const float*)d_in[4];  const float* c1b2 = (const float*)d_in[5];
    const float* c2w1 = (const float*)d_in[6];  const float* c2b1 = (const float*)d_in[7];
    const float* c2w2 = (const float*)d_in[8];  const float* c2b2 = (const float*)d_in[9];
    const float* c3w1 = (const float*)d_in[10]; const float* c3b1 = (const float*)d_in[11];
    const float* c3w2 = (const float*)d_in[12]; const float* c3b2 = (const float*)d_in[13];
    const float* lw   = (const float*)d_in[14]; const float* lb   = (const float*)d_in[15];
    const float* hw1  = (const float*)d_in[16]; const float* hb1  = (const float*)d_in[17];
    const float* hw2  = (const float*)d_in[18]; const float* hb2  = (const float*)d_in[19];
    const float* hw3  = (const float*)d_in[20]; const float* hb3  = (const float*)d_in[21];
    float* out = (float*)d_out;

    // workspace layout: XC | IDX | OVF | pad | union(conv scratch, head scratch)
    float* XC  = (float*)d_ws;                        // NPTS*192
    int*   IDX = (int*)(XC + (size_t)NPTS * 192);     // NPTS*30
    int*   ovf_cnt  = IDX + (size_t)NPTS * KNN;       // 1
    int*   ovf_list = ovf_cnt + 1;                    // NPTS
    float* SCR = (float*)(ovf_list + NPTS + 3);       // 16B-aligned
    // conv-phase view of SCR
    float*    XT   = SCR;                                   // 64*NPTS floats
    double*   S64  = (double*)(XT + (size_t)64 * NPTS);     // NPTS doubles
    float*    S32  = (float*)(S64 + NPTS);                  // NPTS floats
    float*    SMAX = S32 + NPTS;                            // 64 floats
    ushort_t* Xbh  = (ushort_t*)(SMAX + 64);                // NPTS*64 bf16
    ushort_t* Xbl  = Xbh + (size_t)NPTS * 64;               // NPTS*64 bf16
    float*    Dbuf = (float*)(Xbl + (size_t)NPTS * 64);     // NGC*PTS*1024 f32 (16MB)
    float*    Mb   = Dbuf;                                  // alias: D dead before mg_k
    float*    Gb   = Mb + (size_t)NPTS * DIM;
    // head-phase view of SCR
    ushort_t* H1h = (ushort_t*)SCR;                       // CHUNK*1024 bf16
    ushort_t* H1l = H1h + (size_t)CHUNK * 1024;           // CHUNK*1024 bf16
    float* H2 = (float*)(H1l + (size_t)CHUNK * 1024);     // CHUNK*256 fp32
    float* H3 = (float*)H1h;                              // alias: H1 dead when H3 written
    ushort_t* Wlwh = (ushort_t*)(H2 + (size_t)CHUNK * 256);
    ushort_t* Wlwl = Wlwh + 192 * 1024;
    ushort_t* Wh1h = Wlwl + 192 * 1024;
    ushort_t* Wh1l = Wh1h + 1024 * 256;

    run_conv<14, 32>(x,        14,  c1w1, c1b1, c1w2, c1b2, XC + 0,   192,
                     XT, S32, S64, SMAX, Xbh, Xbl, Dbuf, Mb, Gb, IDX, ovf_cnt, ovf_list, stream);
    run_conv<64, 64>(XC + 0,   192, c2w1, c2b1, c2w2, c2b2, XC + 64,  192,
                     XT, S32, S64, SMAX, Xbh, Xbl, Dbuf, Mb, Gb, IDX, ovf_cnt, ovf_list, stream);
    run_conv<64, 64>(XC + 64,  192, c3w1, c3b1, c3w2, c3b2, XC + 128, 192,
                     XT, S32, S64, SMAX, Xbh, Xbl, Dbuf, Mb, Gb, IDX, ovf_cnt, ovf_list, stream);

    wcvt_k<<<(192 * 1024 + 255) / 256, 256, 0, stream>>>(lw,  192,  1024, Wlwh, Wlwl);
    wcvt_k<<<(1024 * 256 + 255) / 256, 256, 0, stream>>>(hw1, 1024, 256,  Wh1h, Wh1l);

    for (int ch = 0; ch < 4; ++ch) {
        const float* a0 = XC + (size_t)ch * CHUNK * 192;
        float* o0 = out + (size_t)ch * CHUNK * 64;
        gemmx_k<true, true, true><<<dim3(1024 / 128, CHUNK / 128), 256, 0, stream>>>(
            a0, nullptr, nullptr, 192, Wlwh, Wlwl, 1024, lb, nullptr, H1h, H1l);
        gemmx_k<false, false, true><<<dim3(256 / 128, CHUNK / 128), 256, 0, stream>>>(
            nullptr, H1h, H1l, 1024, Wh1h, Wh1l, 256, hb1, H2, nullptr, nullptr);
        gemm_k<64, 128, 16, true ><<<dim3(128 / 128, CHUNK / 64), 256, 0, stream>>>(H2, 256, hw2, 128, hb2, H3);
        gemm_k<64, 64, 16, false><<<dim3(64 / 64,   CHUNK / 64), 256, 0, stream>>>(H3, 128, hw3, 64,  hb3, o0);
    }
}

// Round 10
// 1339.617 us; speedup vs baseline: 1.3868x; 1.3868x over previous
//
#include <hip/hip_runtime.h>
#include <hip/hip_bf16.h>
#include <float.h>

#define NG    32
#define PTS   1024
#define NPTS  (NG*PTS)      // 32768
#define KNN   30
#define DIM   64
#define CHUNK 8192

typedef __attribute__((ext_vector_type(8))) short bf16x8;
typedef __attribute__((ext_vector_type(4))) float f32x4;
typedef unsigned short ushort_t;

__device__ inline void bfsplit(float v, ushort_t& h, ushort_t& l) {
    __hip_bfloat16 bh = __float2bfloat16(v);
    float r = v - __bfloat162float(bh);
    __hip_bfloat16 bl = __float2bfloat16(r);
    h = *reinterpret_cast<ushort_t*>(&bh);
    l = *reinterpret_cast<ushort_t*>(&bl);
}

// ---------------------------------------------------------------------------
// prep: S32/S64 + transpose XT[f][p] (for fb_k) + bf16 hi/lo rows [p][KP]
// ---------------------------------------------------------------------------
template<int F, int KP>
__global__ __launch_bounds__(256) void prep_k(const float* __restrict__ X, int ldx,
                                              float* __restrict__ S32,
                                              double* __restrict__ S64,
                                              float* __restrict__ XT,
                                              ushort_t* __restrict__ Xh,
                                              ushort_t* __restrict__ Xl) {
    int p = blockIdx.x * 256 + threadIdx.x;
    float s32 = 0.f;
    double s64 = 0.0;
    #pragma unroll
    for (int f = 0; f < F; ++f) {
        float v = X[(size_t)p * ldx + f];
        s32 = fmaf(v, v, s32);
        s64 = fma((double)v, (double)v, s64);
        XT[(size_t)f * NPTS + p] = v;
        bfsplit(v, Xh[(size_t)p * KP + f], Xl[(size_t)p * KP + f]);
    }
    #pragma unroll
    for (int f = F; f < KP; ++f) {
        Xh[(size_t)p * KP + f] = 0;
        Xl[(size_t)p * KP + f] = 0;
    }
    S32[p] = s32;
    S64[p] = s64;
}

// per-graph max of S32 + zero the overflow counter
__global__ __launch_bounds__(256) void smax_k(const float* __restrict__ S32,
                                              float* __restrict__ SMAX,
                                              int* __restrict__ ovf_cnt) {
    if (blockIdx.x == 0 && threadIdx.x == 0) *ovf_cnt = 0;
    int g = blockIdx.x;
    int lane = threadIdx.x & 63, wv = threadIdx.x >> 6;
    float m = 0.f;
    for (int t = threadIdx.x; t < PTS; t += 256) m = fmaxf(m, S32[(size_t)g * PTS + t]);
    #pragma unroll
    for (int off = 32; off; off >>= 1) m = fmaxf(m, __shfl_xor(m, off));
    __shared__ float wm[4];
    if (lane == 0) wm[wv] = m;
    __syncthreads();
    if (threadIdx.x == 0)
        SMAX[g] = fmaxf(fmaxf(wm[0], wm[1]), fmaxf(wm[2], wm[3]));
}

// ---------------------------------------------------------------------------
// knnf: FUSED knn. Block = 16 points.
// Phase 1 (dist_k math, MFMA bf16 hi/lo 3-product): wave wv computes the
//   16 x 256 D-subtile for j in [wv*256,(wv+1)*256) -> LDS Dt[16][1028].
// Phase 2 (sel_k code verbatim): bisection (eps=1e-4, validated r8) ->
//   ballot compact -> exact f64 rescore -> bitonic -> top-30.
// Overflow (>64 survivors) deferred to fb_k.
// ---------------------------------------------------------------------------
template<int F, int KP>
__global__ __launch_bounds__(256) void knnf_k(const float* __restrict__ X, int ldx,
                                              const ushort_t* __restrict__ Xh,
                                              const ushort_t* __restrict__ Xl,
                                              const float* __restrict__ S32,
                                              const double* __restrict__ S64,
                                              const float* __restrict__ SMAX,
                                              int* __restrict__ IDX,
                                              int* __restrict__ ovf_cnt,
                                              int* __restrict__ ovf_list) {
    constexpr int KS = KP / 32;
    __shared__ float Dt[16][1028];          // pad -> 2-way bank alias (free)
    __shared__ float xis[16][F];
    __shared__ int surv[4][4][64];
    int tid = threadIdx.x, lane = tid & 63, wv = tid >> 6;
    int col16 = lane & 15, grp = lane >> 4, grp8 = grp << 3;
    int i0 = blockIdx.x * 16;
    int base = i0 & ~(PTS - 1);

    for (int l = tid; l < 16 * F; l += 256) {
        int pt = l / F, f = l - pt * F;
        xis[pt][f] = X[(size_t)(i0 + pt) * ldx + f];
    }

    // ---- phase 1: MFMA distances (A-frag rows = the block's 16 points)
    bf16x8 ah[KS], al[KS];
    #pragma unroll
    for (int ks = 0; ks < KS; ++ks) {
        ah[ks] = *reinterpret_cast<const bf16x8*>(&Xh[(size_t)(i0 + col16) * KP + ks * 32 + grp8]);
        al[ks] = *reinterpret_cast<const bf16x8*>(&Xl[(size_t)(i0 + col16) * KP + ks * 32 + grp8]);
    }
    float4 si4 = *reinterpret_cast<const float4*>(&S32[i0 + grp * 4]);
    int jb = base + wv * 256;
    #pragma unroll
    for (int jt = 0; jt < 16; ++jt) {
        int jc = jb + jt * 16 + col16;
        bf16x8 bh[KS], bl[KS];
        #pragma unroll
        for (int ks = 0; ks < KS; ++ks) {
            bh[ks] = *reinterpret_cast<const bf16x8*>(&Xh[(size_t)jc * KP + ks * 32 + grp8]);
            bl[ks] = *reinterpret_cast<const bf16x8*>(&Xl[(size_t)jc * KP + ks * 32 + grp8]);
        }
        float sj = S32[jc];
        f32x4 acc = {0.f, 0.f, 0.f, 0.f};
        #pragma unroll
        for (int ks = 0; ks < KS; ++ks) {
            acc = __builtin_amdgcn_mfma_f32_16x16x32_bf16(ah[ks], bh[ks], acc, 0, 0, 0);
            acc = __builtin_amdgcn_mfma_f32_16x16x32_bf16(ah[ks], bl[ks], acc, 0, 0, 0);
            acc = __builtin_amdgcn_mfma_f32_16x16x32_bf16(al[ks], bh[ks], acc, 0, 0, 0);
        }
        // C layout: col=lane&15, row=grp*4+rg (m89-verified)
        #pragma unroll
        for (int rg = 0; rg < 4; ++rg)
            Dt[grp * 4 + rg][wv * 256 + jt * 16 + col16] = (si4[rg] + sj) - 2.f * acc[rg];
    }
    __syncthreads();

    // ---- phase 2: selection (sel_k verbatim; Dt stride 1028)
    float si[4];
    float d32[4][16];
    #pragma unroll
    for (int ii = 0; ii < 4; ++ii) {
        si[ii] = S32[i0 + wv * 4 + ii];
        #pragma unroll
        for (int m = 0; m < 4; ++m) {
            const float4 v = *reinterpret_cast<const float4*>(
                &Dt[wv * 4 + ii][(m << 8) + (lane << 2)]);
            d32[ii][m * 4 + 0] = v.x; d32[ii][m * 4 + 1] = v.y;
            d32[ii][m * 4 + 2] = v.z; d32[ii][m * 4 + 3] = v.w;
        }
    }
    float smax = SMAX[i0 >> 10];

    const unsigned long long below = (1ull << lane) - 1;
    #pragma unroll
    for (int ii = 0; ii < 4; ++ii) {
        int i = i0 + wv * 4 + ii;
        float lo = -1.f, hi = 2.f * (si[ii] + smax) + 1.f;
        for (int it = 0; it < 32; ++it) {
            float piv = 0.5f * (lo + hi);
            int cnt = 0;
            #pragma unroll
            for (int r = 0; r < 16; ++r)
                cnt += __popcll(__ballot(d32[ii][r] <= piv));
            if (cnt >= KNN) { hi = piv; if (cnt <= 56) break; }
            else lo = piv;
        }
        // eps: >=4x the bf16 hi/lo 3-product distance error bound
        float T = hi + 1.0e-4f * (si[ii] + smax);

        int total = 0;
        #pragma unroll
        for (int r = 0; r < 16; ++r) {
            bool pred = d32[ii][r] <= T;
            unsigned long long mask = __ballot(pred);
            if (pred) {
                int slot = total + __popcll(mask & below);
                if (slot < 64)
                    surv[wv][ii][slot] = ((r >> 2) << 8) + (lane << 2) + (r & 3);
            }
            total += __popcll(mask);
        }
        if (total > 64) {
            if (lane == 0) ovf_list[atomicAdd(ovf_cnt, 1)] = i;
            continue;
        }
        __builtin_amdgcn_wave_barrier();
        asm volatile("s_waitcnt lgkmcnt(0)" ::: "memory");

        double d64 = DBL_MAX;
        int jabs = 0x7fffffff;
        if (lane < total) {
            int jl = surv[wv][ii][lane];
            jabs = base + jl;
            const float* xj = X + (size_t)jabs * ldx;
            double dot = 0.0;
            #pragma unroll
            for (int f = 0; f < F; ++f)
                dot = fma((double)xis[wv * 4 + ii][f], (double)xj[f], dot);
            d64 = (S64[i] + S64[jabs]) - 2.0 * dot;
        }
        #pragma unroll
        for (int k = 2; k <= 64; k <<= 1) {
            #pragma unroll
            for (int s = k >> 1; s > 0; s >>= 1) {
                double od = __shfl_xor(d64, s);
                int oj = __shfl_xor(jabs, s);
                bool otherSmaller = (od < d64) || (od == d64 && oj < jabs);
                bool keepSmaller = (((lane & k) == 0) == ((lane & s) == 0));
                if (otherSmaller == keepSmaller) { d64 = od; jabs = oj; }
            }
        }
        if (lane < KNN) IDX[(size_t)i * KNN + lane] = jabs;
        __builtin_amdgcn_wave_barrier();
    }
}

// ---------------------------------------------------------------------------
// fb_k: exact f64 full scan + 30x min-extract for overflow points only.
// ---------------------------------------------------------------------------
template<int F>
__global__ __launch_bounds__(256) void fb_k(const float* __restrict__ X, int ldx,
                                            const float* __restrict__ XT,
                                            const double* __restrict__ S64,
                                            int* __restrict__ IDX,
                                            const int* __restrict__ ovf_cnt,
                                            const int* __restrict__ ovf_list) {
    int wv = threadIdx.x >> 6, lane = threadIdx.x & 63;
    int novf = *ovf_cnt;
    __shared__ double xis[4][F];
    for (int t = blockIdx.x * 4 + wv; t < novf; t += 64 * 4) {
        int i = ovf_list[t];
        int base = i & ~(PTS - 1);
        if (lane < F) xis[wv][lane] = (double)X[(size_t)i * ldx + lane];
        __builtin_amdgcn_wave_barrier();
        asm volatile("s_waitcnt lgkmcnt(0)" ::: "memory");
        double dd[16];
        #pragma unroll
        for (int m = 0; m < 4; ++m) {
            int j0 = (m << 8) + (lane << 2);
            double d0 = 0.0, d1 = 0.0, d2 = 0.0, d3 = 0.0;
            #pragma unroll
            for (int f = 0; f < F; ++f) {
                double xif = xis[wv][f];
                const float4 xj = *reinterpret_cast<const float4*>(&XT[(size_t)f * NPTS + base + j0]);
                d0 = fma(xif, (double)xj.x, d0);
                d1 = fma(xif, (double)xj.y, d1);
                d2 = fma(xif, (double)xj.z, d2);
                d3 = fma(xif, (double)xj.w, d3);
            }
            dd[m * 4 + 0] = (S64[i] + S64[base + j0 + 0]) - 2.0 * d0;
            dd[m * 4 + 1] = (S64[i] + S64[base + j0 + 1]) - 2.0 * d1;
            dd[m * 4 + 2] = (S64[i] + S64[base + j0 + 2]) - 2.0 * d2;
            dd[m * 4 + 3] = (S64[i] + S64[base + j0 + 3]) - 2.0 * d3;
        }
        for (int k = 0; k < KNN; ++k) {
            double bd = DBL_MAX;
            int bj = 0x7fffffff;
            #pragma unroll
            for (int r = 0; r < 16; ++r) {
                int j = ((r >> 2) << 8) + (lane << 2) + (r & 3);
                if (dd[r] < bd) { bd = dd[r]; bj = j; }
            }
            #pragma unroll
            for (int off = 32; off; off >>= 1) {
                double od = __shfl_xor(bd, off);
                int oj = __shfl_xor(bj, off);
                if (od < bd || (od == bd && oj < bj)) { bd = od; bj = oj; }
            }
            if (((bj >> 2) & 63) == lane) {
                int r = ((bj >> 8) << 2) | (bj & 3);
                #pragma unroll
                for (int rr = 0; rr < 16; ++rr) if (rr == r) dd[rr] = DBL_MAX;
            }
            if (lane == 0) IDX[(size_t)i * KNN + k] = base + bj;
        }
        __builtin_amdgcn_wave_barrier();
    }
}

// ---------------------------------------------------------------------------
// mg: per-point layer-1 decomposition: h1_edge = relu(m_i + g_j)
// ---------------------------------------------------------------------------
template<int F>
__global__ __launch_bounds__(256) void mg_k(const float* __restrict__ X, int ldx,
                                            const float* __restrict__ W1,
                                            const float* __restrict__ B1,
                                            float* __restrict__ Mo, float* __restrict__ Go) {
    int tid = blockIdx.x * 256 + threadIdx.x;
    int pp = tid >> 6, c = tid & 63;
    float m = B1[c], g = 0.f;
    #pragma unroll
    for (int f = 0; f < F; ++f) {
        float xv = X[(size_t)pp * ldx + f];
        float wt = W1[f * DIM + c];
        float wb = W1[(F + f) * DIM + c];
        m = fmaf(xv, wt - wb, m);
        g = fmaf(xv, wb, g);
    }
    Mo[(size_t)pp * DIM + c] = m;
    Go[(size_t)pp * DIM + c] = g;
}

// ---------------------------------------------------------------------------
// edge (MFMA): per wave = 1 point; h1[32x64] @ W2[64x64], bf16 hi/lo 3-product.
// W2 hi/lo PRE-SPLIT+transposed globally (wcvt_k) -> staging is pure copies.
// ---------------------------------------------------------------------------
__global__ __launch_bounds__(256) void edge_k(const int* __restrict__ IDX,
                                              const float* __restrict__ G,
                                              const float* __restrict__ Mb,
                                              const ushort_t* __restrict__ W2h,
                                              const ushort_t* __restrict__ W2l,
                                              const float* __restrict__ B2,
                                              float* __restrict__ OUT, int ldo) {
    __shared__ ushort_t w2hi[64][72], w2lo[64][72];
    __shared__ ushort_t h1hi[4][32][72], h1lo[4][32][72];
    int wv = threadIdx.x >> 6, lane = threadIdx.x & 63;
    int i = blockIdx.x * 4 + wv;
    int col16 = lane & 15, grp = lane >> 4, grp8 = (lane >> 4) << 3;

    for (int l = threadIdx.x; l < 512; l += 256) {      // 512 uint4 = 4096 ushorts
        int c = l >> 3, q = (l & 7) << 3;
        *reinterpret_cast<uint4*>(&w2hi[c][q]) = *reinterpret_cast<const uint4*>(&W2h[c * 64 + q]);
        *reinterpret_cast<uint4*>(&w2lo[c][q]) = *reinterpret_cast<const uint4*>(&W2l[c * 64 + q]);
    }
    __syncthreads();

    float mi = Mb[(size_t)i * DIM + lane];
    const int* idxrow = IDX + (size_t)i * KNN;
    int idxv = (lane < KNN) ? idxrow[lane] : 0;
    float g[KNN];
    #pragma unroll
    for (int nb = 0; nb < KNN; ++nb) {
        int j = __shfl(idxv, nb);
        g[nb] = G[(size_t)j * DIM + lane];
    }
    #pragma unroll
    for (int nb = 0; nb < KNN; ++nb) {
        float h = fmaxf(mi + g[nb], 0.f);
        bfsplit(h, h1hi[wv][nb][lane], h1lo[wv][nb][lane]);
    }
    h1hi[wv][30][lane] = 0; h1lo[wv][30][lane] = 0;
    h1hi[wv][31][lane] = 0; h1lo[wv][31][lane] = 0;
    __builtin_amdgcn_wave_barrier();
    asm volatile("s_waitcnt lgkmcnt(0)" ::: "memory");

    bf16x8 ahi[2][2], alo[2][2];
    #pragma unroll
    for (int m = 0; m < 2; ++m)
        #pragma unroll
        for (int ks = 0; ks < 2; ++ks) {
            ahi[m][ks] = *reinterpret_cast<const bf16x8*>(&h1hi[wv][m * 16 + col16][ks * 32 + grp8]);
            alo[m][ks] = *reinterpret_cast<const bf16x8*>(&h1lo[wv][m * 16 + col16][ks * 32 + grp8]);
        }

    float myout = 0.f;
    #pragma unroll
    for (int n = 0; n < 4; ++n) {
        bf16x8 bhi[2], blo[2];
        #pragma unroll
        for (int ks = 0; ks < 2; ++ks) {
            bhi[ks] = *reinterpret_cast<const bf16x8*>(&w2hi[n * 16 + col16][ks * 32 + grp8]);
            blo[ks] = *reinterpret_cast<const bf16x8*>(&w2lo[n * 16 + col16][ks * 32 + grp8]);
        }
        f32x4 acc0 = {0.f, 0.f, 0.f, 0.f}, acc1 = {0.f, 0.f, 0.f, 0.f};
        #pragma unroll
        for (int ks = 0; ks < 2; ++ks) {
            acc0 = __builtin_amdgcn_mfma_f32_16x16x32_bf16(ahi[0][ks], bhi[ks], acc0, 0, 0, 0);
            acc1 = __builtin_amdgcn_mfma_f32_16x16x32_bf16(ahi[1][ks], bhi[ks], acc1, 0, 0, 0);
            acc0 = __builtin_amdgcn_mfma_f32_16x16x32_bf16(ahi[0][ks], blo[ks], acc0, 0, 0, 0);
            acc1 = __builtin_amdgcn_mfma_f32_16x16x32_bf16(ahi[1][ks], blo[ks], acc1, 0, 0, 0);
            acc0 = __builtin_amdgcn_mfma_f32_16x16x32_bf16(alo[0][ks], bhi[ks], acc0, 0, 0, 0);
            acc1 = __builtin_amdgcn_mfma_f32_16x16x32_bf16(alo[1][ks], bhi[ks], acc1, 0, 0, 0);
        }
        float cm = fmaxf(fmaxf(acc0[0], acc0[1]), fmaxf(acc0[2], acc0[3]));
        cm = fmaxf(cm, fmaxf(acc1[0], acc1[1]));
        if (grp < 3) cm = fmaxf(cm, fmaxf(acc1[2], acc1[3]));
        cm = fmaxf(cm, __shfl_xor(cm, 16));
        cm = fmaxf(cm, __shfl_xor(cm, 32));
        if (grp == n) myout = cm;
    }
    OUT[(size_t)i * ldo + lane] = fmaxf(myout + B2[lane], 0.f);
}

// ---------------------------------------------------------------------------
// wcvt: one-time W[K][N] -> W^T hi/lo bf16 [N][K]
// ---------------------------------------------------------------------------
__global__ __launch_bounds__(256) void wcvt_k(const float* __restrict__ W, int K, int N,
                                              ushort_t* __restrict__ Th,
                                              ushort_t* __restrict__ Tl) {
    int idx = blockIdx.x * 256 + threadIdx.x;
    if (idx >= K * N) return;
    int k = idx / N, n = idx - k * N;
    ushort_t h, l;
    bfsplit(W[idx], h, l);
    Th[(size_t)n * K + k] = h;
    Tl[(size_t)n * K + k] = l;
}

// ---------------------------------------------------------------------------
// gemmx: MFMA GEMM, 128x128 tile, BK=32, bf16 hi/lo 3-product.
// ---------------------------------------------------------------------------
template<bool A32, bool OUT16, bool RELU>
__global__ __launch_bounds__(256) void gemmx_k(
    const float* __restrict__ Afp,
    const ushort_t* __restrict__ Agh, const ushort_t* __restrict__ Agl, int Kd,
    const ushort_t* __restrict__ Bth, const ushort_t* __restrict__ Btl,
    int N, const float* __restrict__ Bias,
    float* __restrict__ Cfp, ushort_t* __restrict__ Cgh, ushort_t* __restrict__ Cgl) {
    constexpr int BM = 128, BN = 128, BKP = 40;
    __shared__ ushort_t Ah[BM][BKP], Al[BM][BKP], Bh[BN][BKP], Bl[BN][BKP];
    int tid = threadIdx.x;
    int lane = tid & 63, wv = tid >> 6;
    int wr = wv >> 1, wc = wv & 1;
    int col16 = lane & 15, grp = lane >> 4, grp8 = grp << 3;
    int bm = blockIdx.y * BM, bn = blockIdx.x * BN;
    f32x4 acc[4][4];
    #pragma unroll
    for (int mf = 0; mf < 4; ++mf)
        #pragma unroll
        for (int nf = 0; nf < 4; ++nf) acc[mf][nf] = (f32x4){0.f, 0.f, 0.f, 0.f};

    for (int k0 = 0; k0 < Kd; k0 += 32) {
        if constexpr (A32) {
            for (int l = tid; l < BM * 8; l += 256) {
                int r = l >> 3, c4 = (l & 7) << 2;
                const float4 a = *reinterpret_cast<const float4*>(&Afp[(size_t)(bm + r) * Kd + k0 + c4]);
                ushort4 h4, l4;
                bfsplit(a.x, h4.x, l4.x);
                bfsplit(a.y, h4.y, l4.y);
                bfsplit(a.z, h4.z, l4.z);
                bfsplit(a.w, h4.w, l4.w);
                *reinterpret_cast<ushort4*>(&Ah[r][c4]) = h4;
                *reinterpret_cast<ushort4*>(&Al[r][c4]) = l4;
            }
        } else {
            for (int l = tid; l < BM * 4; l += 256) {
                int r = l >> 2, q = (l & 3) << 3;
                *reinterpret_cast<uint4*>(&Ah[r][q]) =
                    *reinterpret_cast<const uint4*>(&Agh[(size_t)(bm + r) * Kd + k0 + q]);
                *reinterpret_cast<uint4*>(&Al[r][q]) =
                    *reinterpret_cast<const uint4*>(&Agl[(size_t)(bm + r) * Kd + k0 + q]);
            }
        }
        for (int l = tid; l < BN * 4; l += 256) {
            int n = l >> 2, q = (l & 3) << 3;
            *reinterpret_cast<uint4*>(&Bh[n][q]) =
                *reinterpret_cast<const uint4*>(&Bth[(size_t)(bn + n) * Kd + k0 + q]);
            *reinterpret_cast<uint4*>(&Bl[n][q]) =
                *reinterpret_cast<const uint4*>(&Btl[(size_t)(bn + n) * Kd + k0 + q]);
        }
        __syncthreads();

        bf16x8 afh[4], afl[4], bfh[4], bfl[4];
        #pragma unroll
        for (int mf = 0; mf < 4; ++mf) {
            afh[mf] = *reinterpret_cast<const bf16x8*>(&Ah[wr * 64 + mf * 16 + col16][grp8]);
            afl[mf] = *reinterpret_cast<const bf16x8*>(&Al[wr * 64 + mf * 16 + col16][grp8]);
        }
        #pragma unroll
        for (int nf = 0; nf < 4; ++nf) {
            bfh[nf] = *reinterpret_cast<const bf16x8*>(&Bh[wc * 64 + nf * 16 + col16][grp8]);
            bfl[nf] = *reinterpret_cast<const bf16x8*>(&Bl[wc * 64 + nf * 16 + col16][grp8]);
        }
        #pragma unroll
        for (int mf = 0; mf < 4; ++mf)
            #pragma unroll
            for (int nf = 0; nf < 4; ++nf) {
                acc[mf][nf] = __builtin_amdgcn_mfma_f32_16x16x32_bf16(afh[mf], bfh[nf], acc[mf][nf], 0, 0, 0);
                acc[mf][nf] = __builtin_amdgcn_mfma_f32_16x16x32_bf16(afh[mf], bfl[nf], acc[mf][nf], 0, 0, 0);
                acc[mf][nf] = __builtin_amdgcn_mfma_f32_16x16x32_bf16(afl[mf], bfh[nf], acc[mf][nf], 0, 0, 0);
            }
        __syncthreads();
    }

    #pragma unroll
    for (int nf = 0; nf < 4; ++nf) {
        int col = bn + wc * 64 + nf * 16 + col16;
        float b = Bias[col];
        #pragma unroll
        for (int mf = 0; mf < 4; ++mf) {
            #pragma unroll
            for (int rg = 0; rg < 4; ++rg) {
                int row = bm + wr * 64 + mf * 16 + grp * 4 + rg;
                float v = acc[mf][nf][rg] + b;
                if (RELU) v = fmaxf(v, 0.f);
                if constexpr (OUT16) {
                    bfsplit(v, Cgh[(size_t)row * N + col], Cgl[(size_t)row * N + col]);
                } else {
                    Cfp[(size_t)row * N + col] = v;
                }
            }
        }
    }
}

// ---------------------------------------------------------------------------
// fp32 tiled GEMM (small tail layers)
// ---------------------------------------------------------------------------
template<int TM, int TN, int BK, bool RELU>
__global__ __launch_bounds__(256) void gemm_k(const float* __restrict__ A, int Kd,
                                              const float* __restrict__ W, int N,
                                              const float* __restrict__ Bias,
                                              float* __restrict__ C) {
    constexpr int MM = TM / 16, MN = TN / 16;
    __shared__ __align__(16) float As_t[BK][TM + 4];
    __shared__ __align__(16) float Ws[BK][TN];
    int bm = blockIdx.y * TM, bn = blockIdx.x * TN;
    int tid = threadIdx.x;
    int tr = tid >> 4, tc = tid & 15;
    float acc[MM][MN] = {};
    for (int k0 = 0; k0 < Kd; k0 += BK) {
        #pragma unroll
        for (int l = tid; l < TM * (BK / 4); l += 256) {
            int r = l / (BK / 4), q = l & (BK / 4 - 1);
            const float4 a4 = *reinterpret_cast<const float4*>(&A[(size_t)(bm + r) * Kd + k0 + 4 * q]);
            As_t[4 * q + 0][r] = a4.x;
            As_t[4 * q + 1][r] = a4.y;
            As_t[4 * q + 2][r] = a4.z;
            As_t[4 * q + 3][r] = a4.w;
        }
        #pragma unroll
        for (int l = tid; l < BK * (TN / 4); l += 256) {
            int r = l / (TN / 4), q = l & (TN / 4 - 1);
            *reinterpret_cast<float4*>(&Ws[r][4 * q]) =
                *reinterpret_cast<const float4*>(&W[(size_t)(k0 + r) * N + bn + 4 * q]);
        }
        __syncthreads();
        #pragma unroll
        for (int kk = 0; kk < BK; ++kk) {
            float a[MM], w[MN];
            #pragma unroll
            for (int u = 0; u < MM; u += 4) {
                const float4 v4 = *reinterpret_cast<const float4*>(&As_t[kk][tr * MM + u]);
                a[u] = v4.x; a[u + 1] = v4.y; a[u + 2] = v4.z; a[u + 3] = v4.w;
            }
            #pragma unroll
            for (int v = 0; v < MN; v += 4) {
                const float4 v4 = *reinterpret_cast<const float4*>(&Ws[kk][tc * MN + v]);
                w[v] = v4.x; w[v + 1] = v4.y; w[v + 2] = v4.z; w[v + 3] = v4.w;
            }
            #pragma unroll
            for (int u = 0; u < MM; ++u)
                #pragma unroll
                for (int v = 0; v < MN; ++v)
                    acc[u][v] = fmaf(a[u], w[v], acc[u][v]);
        }
        __syncthreads();
    }
    #pragma unroll
    for (int u = 0; u < MM; ++u) {
        int row = bm + tr * MM + u;
        #pragma unroll
        for (int v = 0; v < MN; v += 4) {
            int col = bn + tc * MN + v;
            float4 o;
            o.x = acc[u][v + 0] + Bias[col + 0];
            o.y = acc[u][v + 1] + Bias[col + 1];
            o.z = acc[u][v + 2] + Bias[col + 2];
            o.w = acc[u][v + 3] + Bias[col + 3];
            if (RELU) {
                o.x = fmaxf(o.x, 0.f); o.y = fmaxf(o.y, 0.f);
                o.z = fmaxf(o.z, 0.f); o.w = fmaxf(o.w, 0.f);
            }
            *reinterpret_cast<float4*>(&C[(size_t)row * N + col]) = o;
        }
    }
}

// ---------------------------------------------------------------------------
template<int F, int KP>
static void run_conv(const float* Xin, int ldx,
                     const float* W1, const float* B1,
                     const float* W2, const float* B2,
                     float* OUT, int ldo,
                     float* XT, float* S32, double* S64, float* SMAX,
                     ushort_t* Xbh, ushort_t* Xbl,
                     float* Mb, float* Gb, int* IDX,
                     int* ovf_cnt, int* ovf_list,
                     ushort_t* W2h, ushort_t* W2l,
                     hipStream_t stream) {
    prep_k<F, KP><<<NPTS / 256, 256, 0, stream>>>(Xin, ldx, S32, S64, XT, Xbh, Xbl);
    smax_k<<<NG, 256, 0, stream>>>(S32, SMAX, ovf_cnt);
    knnf_k<F, KP><<<NPTS / 16, 256, 0, stream>>>(Xin, ldx, Xbh, Xbl, S32, S64, SMAX,
                                                 IDX, ovf_cnt, ovf_list);
    fb_k<F><<<64, 256, 0, stream>>>(Xin, ldx, XT, S64, IDX, ovf_cnt, ovf_list);
    mg_k<F><<<NPTS * DIM / 256, 256, 0, stream>>>(Xin, ldx, W1, B1, Mb, Gb);
    wcvt_k<<<16, 256, 0, stream>>>(W2, 64, 64, W2h, W2l);
    edge_k<<<NPTS / 4, 256, 0, stream>>>(IDX, Gb, Mb, W2h, W2l, B2, OUT, ldo);
}

extern "C" void kernel_launch(void* const* d_in, const int* in_sizes, int n_in,
                              void* d_out, int out_size, void* d_ws, size_t ws_size,
                              hipStream_t stream) {
    (void)in_sizes; (void)n_in; (void)out_size; (void)ws_size;
    const float* x    = (const float*)d_in[0];
    const float* c1w1 = (const float*)d_in[2];  const float* c1b1 = (const float*)d_in[3];
    const float* c1w2 = (const float*)d_in[4];  const float* c1b2 = (const float*)d_in[5];
    const float* c2w1 = (const float*)d_in[6];  const float* c2b1 = (const float*)d_in[7];
    const float* c2w2 = (const float*)d_in[8];  const float* c2b2 = (const float*)d_in[9];
    const float* c3w1 = (const float*)d_in[10]; const float* c3b1 = (const float*)d_in[11];
    const float* c3w2 = (const float*)d_in[12]; const float* c3b2 = (const float*)d_in[13];
    const float* lw   = (const float*)d_in[14]; const float* lb   = (const float*)d_in[15];
    const float* hw1  = (const float*)d_in[16]; const float* hb1  = (const float*)d_in[17];
    const float* hw2  = (const float*)d_in[18]; const float* hb2  = (const float*)d_in[19];
    const float* hw3  = (const float*)d_in[20]; const float* hb3  = (const float*)d_in[21];
    float* out = (float*)d_out;

    // workspace: XC | IDX | OVF | pad | union(conv scratch, head scratch) | W tail
    float* XC  = (float*)d_ws;                        // NPTS*192
    int*   IDX = (int*)(XC + (size_t)NPTS * 192);     // NPTS*30
    int*   ovf_cnt  = IDX + (size_t)NPTS * KNN;       // 1
    int*   ovf_list = ovf_cnt + 1;                    // NPTS
    float* SCR = (float*)(ovf_list + NPTS + 3);       // 16B-aligned
    // conv-phase view of SCR
    float*    XT   = SCR;                                   // 64*NPTS f32
    double*   S64  = (double*)(XT + (size_t)64 * NPTS);     // NPTS f64
    float*    S32  = (float*)(S64 + NPTS);                  // NPTS f32
    float*    SMAX = S32 + NPTS;                            // 64 f32
    ushort_t* Xbh  = (ushort_t*)(SMAX + 64);                // NPTS*64 bf16
    ushort_t* Xbl  = Xbh + (size_t)NPTS * 64;               // NPTS*64 bf16
    float*    Mb   = (float*)(Xbl + (size_t)NPTS * 64);     // NPTS*64 f32
    float*    Gb   = Mb + (size_t)NPTS * DIM;               // NPTS*64 f32
    // head-phase view of SCR
    ushort_t* H1h = (ushort_t*)SCR;                       // CHUNK*1024 bf16
    ushort_t* H1l = H1h + (size_t)CHUNK * 1024;           // CHUNK*1024 bf16
    float* H2 = (float*)(H1l + (size_t)CHUNK * 1024);     // CHUNK*256 f32
    float* H3 = (float*)H1h;                              // alias: H1 dead when H3 written
    // W tail (beyond both phase views' live extents)
    ushort_t* Wlwh = (ushort_t*)(H2 + (size_t)CHUNK * 256);
    ushort_t* Wlwl = Wlwh + 192 * 1024;
    ushort_t* Wh1h = Wlwl + 192 * 1024;
    ushort_t* Wh1l = Wh1h + 1024 * 256;
    ushort_t* W2h  = Wh1l + 1024 * 256;                   // 64*64
    ushort_t* W2l  = W2h + 64 * 64;

    run_conv<14, 32>(x,        14,  c1w1, c1b1, c1w2, c1b2, XC + 0,   192,
                     XT, S32, S64, SMAX, Xbh, Xbl, Mb, Gb, IDX, ovf_cnt, ovf_list,
                     W2h, W2l, stream);
    run_conv<64, 64>(XC + 0,   192, c2w1, c2b1, c2w2, c2b2, XC + 64,  192,
                     XT, S32, S64, SMAX, Xbh, Xbl, Mb, Gb, IDX, ovf_cnt, ovf_list,
                     W2h, W2l, stream);
    run_conv<64, 64>(XC + 64,  192, c3w1, c3b1, c3w2, c3b2, XC + 128, 192,
                     XT, S32, S64, SMAX, Xbh, Xbl, Mb, Gb, IDX, ovf_cnt, ovf_list,
                     W2h, W2l, stream);

    wcvt_k<<<(192 * 1024 + 255) / 256, 256, 0, stream>>>(lw,  192,  1024, Wlwh, Wlwl);
    wcvt_k<<<(1024 * 256 + 255) / 256, 256, 0, stream>>>(hw1, 1024, 256,  Wh1h, Wh1l);

    for (int ch = 0; ch < 4; ++ch) {
        const float* a0 = XC + (size_t)ch * CHUNK * 192;
        float* o0 = out + (size_t)ch * CHUNK * 64;
        gemmx_k<true, true, true><<<dim3(1024 / 128, CHUNK / 128), 256, 0, stream>>>(
            a0, nullptr, nullptr, 192, Wlwh, Wlwl, 1024, lb, nullptr, H1h, H1l);
        gemmx_k<false, false, true><<<dim3(256 / 128, CHUNK / 128), 256, 0, stream>>>(
            nullptr, H1h, H1l, 1024, Wh1h, Wh1l, 256, hb1, H2, nullptr, nullptr);
        gemm_k<64, 128, 16, true ><<<dim3(128 / 128, CHUNK / 64), 256, 0, stream>>>(H2, 256, hw2, 128, hb2, H3);
        gemm_k<64, 64, 16, false><<<dim3(64 / 64,   CHUNK / 64), 256, 0, stream>>>(H3, 128, hw3, 64,  hb3, o0);
    }
}